// Round 1
// baseline (234.854 us; speedup 1.0000x reference)
//
#include <hip/hip_runtime.h>
#include <math.h>

#define TLEN 4096
#define NB   1024
#define NS   10

// ---------------- K0: scaled Laplacian + Chebyshev coefficient tables ------
__global__ void k0_cheb(const float* __restrict__ adj, float* __restrict__ ck) {
  if (threadIdx.x != 0 || blockIdx.x != 0) return;
  double Wm[5][5], L[5][5];
  for (int r = 0; r < 5; ++r)
    for (int c = 0; c < 5; ++c) Wm[r][c] = (double)adj[r*5+c];
  for (int r = 0; r < 5; ++r) {
    double d = 0.0;
    for (int c = 0; c < 5; ++c) d += Wm[r][c];
    for (int c = 0; c < 5; ++c) L[r][c] = (r==c ? d : 0.0) - Wm[r][c];
  }
  // power iteration (L is PSD: dominant |eig| == lambda_max)
  double v[5] = {0.7, -1.1, 0.9, -0.8, 1.3};
  for (int it = 0; it < 96; ++it) {
    double w[5];
    for (int r = 0; r < 5; ++r) {
      double s = 0.0;
      for (int c = 0; c < 5; ++c) s += L[r][c]*v[c];
      w[r] = s;
    }
    double s = fabs(w[0])+fabs(w[1])+fabs(w[2])+fabs(w[3])+fabs(w[4]);
    double inv = 1.0/s;
    for (int r = 0; r < 5; ++r) v[r] = w[r]*inv;
  }
  double num = 0.0, den = 0.0;
  for (int r = 0; r < 5; ++r) {
    double s = 0.0;
    for (int c = 0; c < 5; ++c) s += L[r][c]*v[c];
    num += v[r]*s; den += v[r]*v[r];
  }
  double lam = num/den;
  double Lt[5][5];
  for (int r = 0; r < 5; ++r)
    for (int c = 0; c < 5; ++c)
      Lt[r][c] = 2.0*L[r][c]/lam - (r==c ? 1.0 : 0.0);
  double T2[5][5];
  for (int r = 0; r < 5; ++r)
    for (int c = 0; c < 5; ++c) {
      double s = 0.0;
      for (int j = 0; j < 5; ++j) s += Lt[r][j]*Lt[j][c];
      T2[r][c] = 2.0*s - (r==c ? 1.0 : 0.0);
    }
  // Ck[p][n] = cheb_k at flat index (10p+n) mod 25
  for (int p = 0; p < 10; ++p)
    for (int n = 0; n < 10; ++n) {
      int m = (10*p+n) % 25, r = m/5, c = m%5;
      ck[0*100 + p*10+n] = (float)(r==c ? 1.0 : 0.0);
      ck[1*100 + p*10+n] = (float)Lt[r][c];
      ck[2*100 + p*10+n] = (float)T2[r][c];
    }
}

// ---------------- KA: S partials. S[n,p,t] = sum_b SA[b,p,n]*x[t,b,n] ------
#define TB   64    // t per block
#define BSL  128   // b per slice-block (8 slices)
#define BC   16    // b chunk staged in LDS
#define XSTR 166   // padded LDS row stride (floats) for a 160-float x row

__global__ __launch_bounds__(320) void ka_reduce(const float* __restrict__ x,
    const float* __restrict__ sa, float* __restrict__ ps) {
  __shared__ __align__(16) float xs[TB*XSTR];   // 42.5 KB
  __shared__ __align__(16) float sas[BC*100];   // 6.4 KB
  const int tid = threadIdx.x;
  const int n  = tid >> 5;   // 0..9
  const int tg = tid & 31;   // 0..31
  const int t0 = blockIdx.x * TB;
  const int bbase = blockIdx.y * BSL;
  float acc0[10], acc1[10];
  #pragma unroll
  for (int p = 0; p < 10; ++p) { acc0[p] = 0.f; acc1[p] = 0.f; }

  for (int cch = 0; cch < BSL/BC; ++cch) {
    const int bch = bbase + cch*BC;
    // stage x[t0..t0+64][bch..bch+16][0..10) : 2560 float4, 8 per thread
    #pragma unroll
    for (int r = 0; r < 8; ++r) {
      const int j  = r*320 + tid;        // 0..2559
      const int tt = j / 40;
      const int q  = j - tt*40;          // float4 index within row
      const float4 v = *(const float4*)(x + (size_t)(t0+tt)*(NB*NS)
                                          + (size_t)bch*NS + q*4);
      float2* w = (float2*)(xs + tt*XSTR + q*4);
      w[0] = make_float2(v.x, v.y);
      w[1] = make_float2(v.z, v.w);
    }
    // stage SA[bch..bch+16][0..100): 400 float4
    {
      const float4 v = *(const float4*)(sa + (size_t)bch*100 + tid*4);
      if (tid < 400) *(float4*)(sas + tid*4) = v;
      const int j = tid + 320;
      if (j < 400) {
        const float4 v2 = *(const float4*)(sa + (size_t)bch*100 + j*4);
        *(float4*)(sas + j*4) = v2;
      }
    }
    __syncthreads();
    #pragma unroll
    for (int bb = 0; bb < BC; ++bb) {
      const float xv0 = xs[(2*tg  )*XSTR + bb*NS + n];
      const float xv1 = xs[(2*tg+1)*XSTR + bb*NS + n];
      const float* sp = sas + bb*100 + n;   // SA[bb][p][n], broadcast reads
      #pragma unroll
      for (int p = 0; p < 10; ++p) {
        const float s = sp[p*10];
        acc0[p] += s*xv0;
        acc1[p] += s*xv1;
      }
    }
    __syncthreads();
  }
  // write partials: PS[slice][t][n*10+p]
  {
    const int t_a = t0 + 2*tg;
    float* d0 = ps + ((size_t)blockIdx.y*TLEN + t_a)*100 + n*10;
    float* d1 = d0 + 100;
    #pragma unroll
    for (int p = 0; p < 10; ++p) { d0[p] = acc0[p]; d1[p] = acc1[p]; }
  }
}

// ---------------- KC: out[t,b,n] = relu( sum_p S[n,p,t] * W[p,n,b] ) -------
#define TT 8
__global__ __launch_bounds__(256) void kc_out(const float* __restrict__ theta,
    const float* __restrict__ ck, const float* __restrict__ ps,
    float* __restrict__ out) {
  __shared__ __align__(16) float S[TT*120];   // [tt][n][12] padded
  __shared__ float C[300];
  const int tid = threadIdx.x;
  const int t0 = blockIdx.x * TT;
  const int b  = blockIdx.y * 256 + tid;
  for (int j = tid; j < 300; j += 256) C[j] = ck[j];
  for (int j = tid; j < TT*100; j += 256) {
    const int tt = j / 100, q = j - tt*100;
    float s = 0.f;
    #pragma unroll
    for (int sl = 0; sl < 8; ++sl)
      s += ps[((size_t)sl*TLEN + (t0+tt))*100 + q];
    S[tt*120 + (q/10)*12 + (q - (q/10)*10)] = s;
  }
  __syncthreads();
  // per-thread W[p][n] for this b
  float W[10][10];
  #pragma unroll
  for (int p = 0; p < 10; ++p) {
    const float th0 = theta[          p*NB + b];
    const float th1 = theta[10*NB  +  p*NB + b];
    const float th2 = theta[20*NB  +  p*NB + b];
    #pragma unroll
    for (int nn = 0; nn < 10; ++nn)
      W[p][nn] = C[p*10+nn]*th0 + C[100+p*10+nn]*th1 + C[200+p*10+nn]*th2;
  }
  for (int tt = 0; tt < TT; ++tt) {
    float acc[10];
    #pragma unroll
    for (int nn = 0; nn < 10; ++nn) {
      const float4 s0 = *(const float4*)(S + tt*120 + nn*12);
      const float4 s1 = *(const float4*)(S + tt*120 + nn*12 + 4);
      const float2 s2 = *(const float2*)(S + tt*120 + nn*12 + 8);
      acc[nn] = s0.x*W[0][nn] + s0.y*W[1][nn] + s0.z*W[2][nn] + s0.w*W[3][nn]
              + s1.x*W[4][nn] + s1.y*W[5][nn] + s1.z*W[6][nn] + s1.w*W[7][nn]
              + s2.x*W[8][nn] + s2.y*W[9][nn];
    }
    float* o = out + (size_t)(t0+tt)*(NB*NS) + (size_t)b*NS;
    #pragma unroll
    for (int h = 0; h < 5; ++h) {
      const float2 v = make_float2(fmaxf(acc[2*h], 0.f), fmaxf(acc[2*h+1], 0.f));
      *(float2*)(o + 2*h) = v;
    }
  }
}

extern "C" void kernel_launch(void* const* d_in, const int* in_sizes, int n_in,
                              void* d_out, int out_size, void* d_ws, size_t ws_size,
                              hipStream_t stream) {
  const float* x   = (const float*)d_in[0];  // (4096,1024,10)
  const float* adj = (const float*)d_in[1];  // (5,5)
  const float* sa  = (const float*)d_in[2];  // (1024,10,10)
  const float* th  = (const float*)d_in[3];  // (3,10,1024)
  float* out = (float*)d_out;
  float* ws  = (float*)d_ws;
  float* ck  = ws;                // 300 floats
  float* ps  = ws + 1024;         // 8*4096*100 floats = 13.1 MB
  hipLaunchKernelGGL(k0_cheb,   dim3(1), dim3(64), 0, stream, adj, ck);
  hipLaunchKernelGGL(ka_reduce, dim3(TLEN/TB, 8), dim3(320), 0, stream, x, sa, ps);
  hipLaunchKernelGGL(kc_out,    dim3(TLEN/TT, NB/256), dim3(256), 0, stream, th, ck, ps, out);
}

// Round 2
// 117.629 us; speedup vs baseline: 1.9966x; 1.9966x over previous
//
#include <hip/hip_runtime.h>
#include <math.h>

#define TLEN 4096
#define NB   1024
#define NS   10

// ---------------- K0: scaled Laplacian + Chebyshev coefficient tables ------
__global__ void k0_cheb(const float* __restrict__ adj, float* __restrict__ ck) {
  if (threadIdx.x != 0 || blockIdx.x != 0) return;
  double Wm[5][5], L[5][5];
  for (int r = 0; r < 5; ++r)
    for (int c = 0; c < 5; ++c) Wm[r][c] = (double)adj[r*5+c];
  for (int r = 0; r < 5; ++r) {
    double d = 0.0;
    for (int c = 0; c < 5; ++c) d += Wm[r][c];
    for (int c = 0; c < 5; ++c) L[r][c] = (r==c ? d : 0.0) - Wm[r][c];
  }
  double v[5] = {0.7, -1.1, 0.9, -0.8, 1.3};
  for (int it = 0; it < 96; ++it) {
    double w[5];
    for (int r = 0; r < 5; ++r) {
      double s = 0.0;
      for (int c = 0; c < 5; ++c) s += L[r][c]*v[c];
      w[r] = s;
    }
    double s = fabs(w[0])+fabs(w[1])+fabs(w[2])+fabs(w[3])+fabs(w[4]);
    double inv = 1.0/s;
    for (int r = 0; r < 5; ++r) v[r] = w[r]*inv;
  }
  double num = 0.0, den = 0.0;
  for (int r = 0; r < 5; ++r) {
    double s = 0.0;
    for (int c = 0; c < 5; ++c) s += L[r][c]*v[c];
    num += v[r]*s; den += v[r]*v[r];
  }
  double lam = num/den;
  double Lt[5][5];
  for (int r = 0; r < 5; ++r)
    for (int c = 0; c < 5; ++c)
      Lt[r][c] = 2.0*L[r][c]/lam - (r==c ? 1.0 : 0.0);
  double T2[5][5];
  for (int r = 0; r < 5; ++r)
    for (int c = 0; c < 5; ++c) {
      double s = 0.0;
      for (int j = 0; j < 5; ++j) s += Lt[r][j]*Lt[j][c];
      T2[r][c] = 2.0*s - (r==c ? 1.0 : 0.0);
    }
  for (int p = 0; p < 10; ++p)
    for (int n = 0; n < 10; ++n) {
      int m = (10*p+n) % 25, r = m/5, c = m%5;
      ck[0*100 + p*10+n] = (float)(r==c ? 1.0 : 0.0);
      ck[1*100 + p*10+n] = (float)Lt[r][c];
      ck[2*100 + p*10+n] = (float)T2[r][c];
    }
}

// ---------------- KA: S partials. S[n,p,t] = sum_b SA[b,p,n]*x[t,b,n] ------
#define TB   64    // t per block
#define BSL  128   // b per slice-block (8 slices)
#define BC   16    // b chunk staged in LDS
#define XSTR 166   // padded LDS row stride (floats); lane stride 166w = 2-way

__global__ __launch_bounds__(320) void ka_reduce(const float* __restrict__ x,
    const float* __restrict__ sa, float* __restrict__ ps) {
  __shared__ __align__(16) float xs[TB*XSTR];     // 42.5 KB
  __shared__ __align__(16) float sas[BC*120];     // [bb][n][12] padded, 7.7 KB
  const int tid = threadIdx.x;
  const int n  = tid >> 5;   // 0..9
  const int tg = tid & 31;   // 0..31
  const int t0 = blockIdx.x * TB;
  const int bbase = blockIdx.y * BSL;

  // precomputed staging geometry (constant per thread)
  const int stt = tid / 40;          // 0..7   (t row within first group)
  const int sq  = tid - stt*40;      // 0..39  (float4 index within 160-float row)
  // SA staging write offsets (indices constant across chunks)
  int saw0[4], saw1[4];
  {
    const int jj = tid;              // first float4 id (<400 always, tid<320)
    #pragma unroll
    for (int e = 0; e < 4; ++e) {
      const int g = jj*4 + e, bb = g/100, r = g - bb*100, p = r/10, nn = r - p*10;
      saw0[e] = bb*120 + nn*12 + p;
    }
    const int j2 = tid + 320;        // second float4 id, valid if tid<80
    #pragma unroll
    for (int e = 0; e < 4; ++e) {
      const int g = j2*4 + e, bb = g/100, r = g - bb*100, p = r/10, nn = r - p*10;
      saw1[e] = bb*120 + nn*12 + p;
    }
  }

  float acc0[10], acc1[10];
  #pragma unroll
  for (int p = 0; p < 10; ++p) { acc0[p] = 0.f; acc1[p] = 0.f; }

  for (int cch = 0; cch < BSL/BC; ++cch) {
    const int bch = bbase + cch*BC;
    // stage x[t0..t0+64][bch..bch+16][:] -> xs[t][bb*10+n]
    #pragma unroll
    for (int r = 0; r < 8; ++r) {
      const int tt = stt + 8*r;
      const float4 v = *(const float4*)(x + (size_t)(t0+tt)*(NB*NS)
                                          + (size_t)bch*NS + sq*4);
      float2* w = (float2*)(xs + tt*XSTR + sq*4);
      w[0] = make_float2(v.x, v.y);
      w[1] = make_float2(v.z, v.w);
    }
    // stage SA[bch..bch+16][p][n] -> sas[bb][n][12]+p (transposed, padded)
    {
      const float4 v = *(const float4*)(sa + (size_t)bch*100 + (size_t)tid*4);
      sas[saw0[0]] = v.x; sas[saw0[1]] = v.y;
      sas[saw0[2]] = v.z; sas[saw0[3]] = v.w;
      if (tid < 80) {
        const float4 v2 = *(const float4*)(sa + (size_t)bch*100 + (size_t)(tid+320)*4);
        sas[saw1[0]] = v2.x; sas[saw1[1]] = v2.y;
        sas[saw1[2]] = v2.z; sas[saw1[3]] = v2.w;
      }
    }
    __syncthreads();
    #pragma unroll
    for (int bb = 0; bb < BC; ++bb) {
      const float xv0 = xs[ tg      *XSTR + bb*NS + n];
      const float xv1 = xs[(tg+32)  *XSTR + bb*NS + n];
      const float* sp = sas + bb*120 + n*12;
      const float4 sA = *(const float4*)(sp);
      const float4 sB = *(const float4*)(sp + 4);
      const float2 sC = *(const float2*)(sp + 8);
      acc0[0] += sA.x*xv0; acc1[0] += sA.x*xv1;
      acc0[1] += sA.y*xv0; acc1[1] += sA.y*xv1;
      acc0[2] += sA.z*xv0; acc1[2] += sA.z*xv1;
      acc0[3] += sA.w*xv0; acc1[3] += sA.w*xv1;
      acc0[4] += sB.x*xv0; acc1[4] += sB.x*xv1;
      acc0[5] += sB.y*xv0; acc1[5] += sB.y*xv1;
      acc0[6] += sB.z*xv0; acc1[6] += sB.z*xv1;
      acc0[7] += sB.w*xv0; acc1[7] += sB.w*xv1;
      acc0[8] += sC.x*xv0; acc1[8] += sC.x*xv1;
      acc0[9] += sC.y*xv0; acc1[9] += sC.y*xv1;
    }
    __syncthreads();
  }
  // write partials: PS[slice][t][n*10+p], thread owns t0+tg and t0+tg+32
  {
    float* d0 = ps + ((size_t)blockIdx.y*TLEN + t0 + tg)*100 + n*10;
    float* d1 = d0 + (size_t)32*100;
    #pragma unroll
    for (int p = 0; p < 10; ++p) { d0[p] = acc0[p]; d1[p] = acc1[p]; }
  }
}

// ---------------- KC: out[t,b,n] = relu( sum_p S[n,p,t] * W[p,n,b] ) -------
#define TT 8
__global__ __launch_bounds__(256) void kc_out(const float* __restrict__ theta,
    const float* __restrict__ ck, const float* __restrict__ ps,
    float* __restrict__ out) {
  __shared__ __align__(16) float S[TT*120];     // [tt][n][12] padded
  __shared__ float C[300];
  __shared__ __align__(16) float stg[2][2560];  // double-buffered store stage
  const int tid = threadIdx.x;
  const int t0 = blockIdx.x * TT;
  const int b  = blockIdx.y * 256 + tid;
  for (int j = tid; j < 300; j += 256) C[j] = ck[j];
  for (int j = tid; j < TT*100; j += 256) {
    const int tt = j / 100, q = j - tt*100;
    float s = 0.f;
    #pragma unroll
    for (int sl = 0; sl < 8; ++sl)
      s += ps[((size_t)sl*TLEN + (t0+tt))*100 + q];
    S[tt*120 + (q/10)*12 + (q - (q/10)*10)] = s;
  }
  __syncthreads();
  // per-thread W[p][n] for this b
  float W[10][10];
  #pragma unroll
  for (int p = 0; p < 10; ++p) {
    const float th0 = theta[          p*NB + b];
    const float th1 = theta[10*NB  +  p*NB + b];
    const float th2 = theta[20*NB  +  p*NB + b];
    #pragma unroll
    for (int nn = 0; nn < 10; ++nn)
      W[p][nn] = C[p*10+nn]*th0 + C[100+p*10+nn]*th1 + C[200+p*10+nn]*th2;
  }
  for (int tt = 0; tt < TT; ++tt) {
    float acc[10];
    #pragma unroll
    for (int nn = 0; nn < 10; ++nn) {
      const float4 s0 = *(const float4*)(S + tt*120 + nn*12);
      const float4 s1 = *(const float4*)(S + tt*120 + nn*12 + 4);
      const float2 s2 = *(const float2*)(S + tt*120 + nn*12 + 8);
      acc[nn] = s0.x*W[0][nn] + s0.y*W[1][nn] + s0.z*W[2][nn] + s0.w*W[3][nn]
              + s1.x*W[4][nn] + s1.y*W[5][nn] + s1.z*W[6][nn] + s1.w*W[7][nn]
              + s2.x*W[8][nn] + s2.y*W[9][nn];
    }
    float* sg = stg[tt & 1];
    #pragma unroll
    for (int nn = 0; nn < 10; ++nn)
      sg[tid*10 + nn] = fmaxf(acc[nn], 0.f);
    __syncthreads();
    const float4* sp = (const float4*)sg;
    float4* op = (float4*)(out + (size_t)(t0+tt)*(NB*NS)
                               + (size_t)blockIdx.y*2560);
    op[tid]       = sp[tid];
    op[tid + 256] = sp[tid + 256];
    if (tid < 128) op[tid + 512] = sp[tid + 512];
  }
}

extern "C" void kernel_launch(void* const* d_in, const int* in_sizes, int n_in,
                              void* d_out, int out_size, void* d_ws, size_t ws_size,
                              hipStream_t stream) {
  const float* x   = (const float*)d_in[0];  // (4096,1024,10)
  const float* adj = (const float*)d_in[1];  // (5,5)
  const float* sa  = (const float*)d_in[2];  // (1024,10,10)
  const float* th  = (const float*)d_in[3];  // (3,10,1024)
  float* out = (float*)d_out;
  float* ws  = (float*)d_ws;
  float* ck  = ws;                // 300 floats
  float* ps  = ws + 1024;         // 8*4096*100 floats = 13.1 MB
  hipLaunchKernelGGL(k0_cheb,   dim3(1), dim3(64), 0, stream, adj, ck);
  hipLaunchKernelGGL(ka_reduce, dim3(TLEN/TB, 8), dim3(320), 0, stream, x, sa, ps);
  hipLaunchKernelGGL(kc_out,    dim3(TLEN/TT, NB/256), dim3(256), 0, stream, th, ck, ps, out);
}